// Round 1
// baseline (403.849 us; speedup 1.0000x reference)
//
#include <hip/hip_runtime.h>

// AdditiveAttention: B=32, S=2048, H=1024, fp32.
// attn = softmax_s(lstm . w1)  (softmax invariant to per-row const (fh.w2 + b) -> skip it)
// context = attn . lstm
// Single fused pass over lstm (268 MB read once), per-wave exp-weighted partials,
// then tiny combine + attn kernels.

#define B_ 32
#define S_ 2048
#define H_ 1024
#define ROWS 32                          // s-rows per wave
#define WAVES_PER_BATCH (S_ / ROWS)      // 64
#define NWAVE (B_ * WAVES_PER_BATCH)     // 2048
#define NBLK (NWAVE / 4)                 // 512 blocks of 256 threads (2 per CU)

__global__ __launch_bounds__(256) void fused_pass(
    const float* __restrict__ lstm, const float* __restrict__ W,
    float* __restrict__ scores, float* __restrict__ part, float* __restrict__ lpart)
{
    const int tid  = threadIdx.x;
    const int wave = tid >> 6;
    const int lane = tid & 63;
    const int gw   = blockIdx.x * 4 + wave;   // global wave id, 0..2047
    const int b    = gw >> 6;                 // 64 waves per batch
    const int s0   = (gw & 63) * ROWS;

    // w1 fragment: lane owns h = q*256 + lane*4 + k  (fully coalesced float4 per q)
    float4 w[4];
#pragma unroll
    for (int q = 0; q < 4; ++q)
        w[q] = *(const float4*)(W + q * 256 + lane * 4);

    float4 acc[4];
#pragma unroll
    for (int q = 0; q < 4; ++q) acc[q] = make_float4(0.f, 0.f, 0.f, 0.f);
    float l = 0.f;

    const float* base = lstm + ((size_t)b * S_ + s0) * H_ + lane * 4;

    // software-pipelined row loads
    float4 v[4];
#pragma unroll
    for (int q = 0; q < 4; ++q) v[q] = *(const float4*)(base + q * 256);

#pragma unroll
    for (int r = 0; r < ROWS; ++r) {
        float4 nv[4];
        if (r + 1 < ROWS) {
            const float* nb = base + (size_t)(r + 1) * H_;
#pragma unroll
            for (int q = 0; q < 4; ++q) nv[q] = *(const float4*)(nb + q * 256);
        }
        // per-lane partial dot over 16 elems
        float d = v[0].x * w[0].x + v[0].y * w[0].y + v[0].z * w[0].z + v[0].w * w[0].w;
#pragma unroll
        for (int q = 1; q < 4; ++q)
            d += v[q].x * w[q].x + v[q].y * w[q].y + v[q].z * w[q].z + v[q].w * w[q].w;
        // wave-wide butterfly reduce: all 64 lanes end with the full score
#pragma unroll
        for (int off = 32; off >= 1; off >>= 1)
            d += __shfl_xor(d, off, 64);
        if (lane == 0) scores[(size_t)b * S_ + s0 + r] = d;
        const float e = __expf(d);
        l += e;
#pragma unroll
        for (int q = 0; q < 4; ++q) {
            acc[q].x += e * v[q].x; acc[q].y += e * v[q].y;
            acc[q].z += e * v[q].z; acc[q].w += e * v[q].w;
        }
        if (r + 1 < ROWS) {
#pragma unroll
            for (int q = 0; q < 4; ++q) v[q] = nv[q];
        }
    }

    float* pp = part + (size_t)gw * H_ + lane * 4;
#pragma unroll
    for (int q = 0; q < 4; ++q) *(float4*)(pp + q * 256) = acc[q];
    if (lane == 0) lpart[gw] = l;
}

// context[b,h] = (sum_j part[b*64+j][h]) / L_b ; also stash L_b for the attn kernel
__global__ __launch_bounds__(128) void combine_k(
    const float* __restrict__ part, const float* __restrict__ lpart,
    float* __restrict__ ctx_out, float* __restrict__ Lws)
{
    const int b = blockIdx.x;
    const int h = blockIdx.y * 128 + threadIdx.x;
    float L = 0.f;
#pragma unroll
    for (int j = 0; j < WAVES_PER_BATCH; ++j)
        L += lpart[b * WAVES_PER_BATCH + j];
    float sum = 0.f;
#pragma unroll 8
    for (int j = 0; j < WAVES_PER_BATCH; ++j)
        sum += part[(size_t)(b * WAVES_PER_BATCH + j) * H_ + h];
    ctx_out[(size_t)b * H_ + h] = sum / L;
    if (blockIdx.y == 0 && threadIdx.x == 0) Lws[b] = L;
}

__global__ __launch_bounds__(256) void attn_k(
    const float* __restrict__ scores, const float* __restrict__ Lws,
    float* __restrict__ attn_out)
{
    const int i = blockIdx.x * 256 + threadIdx.x;  // float4 index, 0..16383
    const int b = i >> 9;                          // (i*4)/2048
    const float invL = 1.0f / Lws[b];
    const float4 sc = ((const float4*)scores)[i];
    float4 o;
    o.x = __expf(sc.x) * invL;
    o.y = __expf(sc.y) * invL;
    o.z = __expf(sc.z) * invL;
    o.w = __expf(sc.w) * invL;
    ((float4*)attn_out)[i] = o;
}

extern "C" void kernel_launch(void* const* d_in, const int* in_sizes, int n_in,
                              void* d_out, int out_size, void* d_ws, size_t ws_size,
                              hipStream_t stream)
{
    const float* lstm = (const float*)d_in[0];
    // d_in[1] = final_hidden, d_in[3] = b : provably irrelevant (softmax shift-invariance)
    const float* W    = (const float*)d_in[2];

    float* out  = (float*)d_out;
    float* ctx  = out;               // 32*1024
    float* attn = out + B_ * H_;     // 32*2048

    float* ws     = (float*)d_ws;
    float* scores = ws;                              // 65536 floats
    float* part   = ws + (size_t)B_ * S_;            // 2048*1024 floats
    float* lpart  = part + (size_t)NWAVE * H_;       // 2048 floats
    float* Lws    = lpart + NWAVE;                   // 32 floats

    fused_pass<<<NBLK, 256, 0, stream>>>(lstm, W, scores, part, lpart);
    combine_k<<<dim3(B_, H_ / 128), 128, 0, stream>>>(part, lpart, ctx, Lws);
    attn_k<<<(B_ * S_) / (4 * 256), 256, 0, stream>>>(scores, Lws, attn);
}

// Round 2
// 372.334 us; speedup vs baseline: 1.0846x; 1.0846x over previous
//
#include <hip/hip_runtime.h>

// AdditiveAttention: B=32, S=2048, H=1024, fp32.
// attn = softmax_s(lstm . w1)   (fh.w2 + b is a per-row constant -> softmax-invariant, skipped)
// context = attn . lstm
// Single fused pass over lstm (268 MB read once). R1: ROWS=16 (4 blocks/CU) and
// 4-row-batched butterfly reduce (4-way ILP on the shuffle chain).

#define B_ 32
#define S_ 2048
#define H_ 1024
#define ROWS 16                          // s-rows per wave
#define WAVES_PER_BATCH (S_ / ROWS)      // 128
#define NWAVE (B_ * WAVES_PER_BATCH)     // 4096
#define NBLK (NWAVE / 4)                 // 1024 blocks of 256 threads (4 per CU)

__global__ __launch_bounds__(256) void fused_pass(
    const float* __restrict__ lstm, const float* __restrict__ W,
    float* __restrict__ esc, float* __restrict__ part, float* __restrict__ lpart)
{
    const int tid  = threadIdx.x;
    const int wave = tid >> 6;
    const int lane = tid & 63;
    const int gw   = blockIdx.x * 4 + wave;   // global wave id, 0..4095
    const int b    = gw >> 7;                 // 128 waves per batch row
    const int s0   = (gw & 127) * ROWS;

    // w1 fragment: lane owns h = q*256 + lane*4 + k
    float4 w[4];
#pragma unroll
    for (int q = 0; q < 4; ++q)
        w[q] = *(const float4*)(W + q * 256 + lane * 4);

    float4 acc[4];
#pragma unroll
    for (int q = 0; q < 4; ++q) acc[q] = make_float4(0.f, 0.f, 0.f, 0.f);
    float l = 0.f;

    const float* base = lstm + ((size_t)b * S_ + s0) * H_ + lane * 4;

#pragma unroll
    for (int t = 0; t < ROWS / 4; ++t) {      // 4 batches of 4 rows
        const float* rb = base + (size_t)(t * 4) * H_;
        float4 v[4][4];
#pragma unroll
        for (int r = 0; r < 4; ++r)
#pragma unroll
            for (int q = 0; q < 4; ++q)
                v[r][q] = *(const float4*)(rb + (size_t)r * H_ + q * 256);

        float d[4];
#pragma unroll
        for (int r = 0; r < 4; ++r) {
            float s = v[r][0].x * w[0].x + v[r][0].y * w[0].y
                    + v[r][0].z * w[0].z + v[r][0].w * w[0].w;
#pragma unroll
            for (int q = 1; q < 4; ++q)
                s += v[r][q].x * w[q].x + v[r][q].y * w[q].y
                   + v[r][q].z * w[q].z + v[r][q].w * w[q].w;
            d[r] = s;
        }
        // 4 independent 64-lane butterflies, interleaved (4-way ILP per level)
#pragma unroll
        for (int off = 32; off >= 1; off >>= 1) {
#pragma unroll
            for (int r = 0; r < 4; ++r)
                d[r] += __shfl_xor(d[r], off, 64);
        }
        float e[4];
#pragma unroll
        for (int r = 0; r < 4; ++r) e[r] = __expf(d[r]);
        if (lane == 0)
            *(float4*)(esc + (size_t)b * S_ + s0 + t * 4) =
                make_float4(e[0], e[1], e[2], e[3]);
        l += (e[0] + e[1]) + (e[2] + e[3]);
#pragma unroll
        for (int r = 0; r < 4; ++r) {
#pragma unroll
            for (int q = 0; q < 4; ++q) {
                acc[q].x = fmaf(e[r], v[r][q].x, acc[q].x);
                acc[q].y = fmaf(e[r], v[r][q].y, acc[q].y);
                acc[q].z = fmaf(e[r], v[r][q].z, acc[q].z);
                acc[q].w = fmaf(e[r], v[r][q].w, acc[q].w);
            }
        }
    }

    float* pp = part + (size_t)gw * H_ + lane * 4;
#pragma unroll
    for (int q = 0; q < 4; ++q) *(float4*)(pp + q * 256) = acc[q];
    if (lane == 0) lpart[gw] = l;
}

// context[b,h] = (sum_j part[b*128+j][h]) / L_b ; stash L_b
__global__ __launch_bounds__(256) void combine_k(
    const float* __restrict__ part, const float* __restrict__ lpart,
    float* __restrict__ ctx_out, float* __restrict__ Lws)
{
    const int b = blockIdx.x;
    const int h = blockIdx.y * 256 + threadIdx.x;
    float L = 0.f;
#pragma unroll 16
    for (int j = 0; j < WAVES_PER_BATCH; ++j)
        L += lpart[b * WAVES_PER_BATCH + j];
    float sum = 0.f;
#pragma unroll 8
    for (int j = 0; j < WAVES_PER_BATCH; ++j)
        sum += part[(size_t)(b * WAVES_PER_BATCH + j) * H_ + h];
    ctx_out[(size_t)b * H_ + h] = sum / L;
    if (blockIdx.y == 0 && threadIdx.x == 0) Lws[b] = L;
}

__global__ __launch_bounds__(256) void attn_k(
    const float* __restrict__ esc, const float* __restrict__ Lws,
    float* __restrict__ attn_out)
{
    const int i = blockIdx.x * 256 + threadIdx.x;  // float4 index, 0..16383
    const int b = i >> 9;
    const float invL = 1.0f / Lws[b];
    const float4 e = ((const float4*)esc)[i];
    float4 o;
    o.x = e.x * invL; o.y = e.y * invL; o.z = e.z * invL; o.w = e.w * invL;
    ((float4*)attn_out)[i] = o;
}

extern "C" void kernel_launch(void* const* d_in, const int* in_sizes, int n_in,
                              void* d_out, int out_size, void* d_ws, size_t ws_size,
                              hipStream_t stream)
{
    const float* lstm = (const float*)d_in[0];
    // d_in[1] = final_hidden, d_in[3] = b : irrelevant under softmax shift-invariance
    const float* W    = (const float*)d_in[2];

    float* out  = (float*)d_out;
    float* ctx  = out;               // 32*1024
    float* attn = out + B_ * H_;     // 32*2048

    float* ws    = (float*)d_ws;
    float* esc   = ws;                               // 65536 floats (exp(score))
    float* part  = ws + (size_t)B_ * S_;             // 4096*1024 floats
    float* lpart = part + (size_t)NWAVE * H_;        // 4096 floats
    float* Lws   = lpart + NWAVE;                    // 32 floats

    fused_pass<<<NBLK, 256, 0, stream>>>(lstm, W, esc, part, lpart);
    combine_k<<<dim3(B_, H_ / 256), 256, 0, stream>>>(part, lpart, ctx, Lws);
    attn_k<<<(B_ * S_) / (4 * 256), 256, 0, stream>>>(esc, Lws, attn);
}

// Round 3
// 365.704 us; speedup vs baseline: 1.1043x; 1.0181x over previous
//
#include <hip/hip_runtime.h>

// AdditiveAttention: B=32, S=2048, H=1024, fp32.
// attn = softmax_s(lstm . w1)   (fh.w2 + b is per-row constant -> softmax-invariant, skipped)
// context = attn . lstm
// R3: 2-row double-buffered batches (loads always in flight), block-level LDS
// combine of wave partials (part traffic 4x smaller).

#define B_ 32
#define S_ 2048
#define H_ 1024
#define ROWS 16                          // s-rows per wave
#define BATCH2 (ROWS / 2)                // 8 double-buffered 2-row batches
#define WAVES_PER_BATCH (S_ / ROWS)      // 128
#define NWAVE (B_ * WAVES_PER_BATCH)     // 4096
#define NBLK (NWAVE / 4)                 // 1024 blocks (4 per CU)
#define BLK_PER_B (NBLK / B_)            // 32 blocks per batch row

__global__ __launch_bounds__(256) void fused_pass(
    const float* __restrict__ lstm, const float* __restrict__ W,
    float* __restrict__ esc, float* __restrict__ part, float* __restrict__ lblk)
{
    const int tid  = threadIdx.x;
    const int wave = tid >> 6;
    const int lane = tid & 63;
    const int gw   = blockIdx.x * 4 + wave;   // 0..4095
    const int b    = gw >> 7;                 // 128 waves per batch row
    const int s0   = (gw & 127) * ROWS;

    float4 w[4];
#pragma unroll
    for (int q = 0; q < 4; ++q)
        w[q] = *(const float4*)(W + q * 256 + lane * 4);

    float4 acc[4];
#pragma unroll
    for (int q = 0; q < 4; ++q) acc[q] = make_float4(0.f, 0.f, 0.f, 0.f);
    float l = 0.f;

    const float* base = lstm + ((size_t)b * S_ + s0) * H_ + lane * 4;

    float4 va[2][4], vb[2][4];
#pragma unroll
    for (int r = 0; r < 2; ++r)
#pragma unroll
        for (int q = 0; q < 4; ++q)
            va[r][q] = *(const float4*)(base + (size_t)r * H_ + q * 256);

#pragma unroll
    for (int t = 0; t < BATCH2; ++t) {
        float4 (*cur)[4] = (t & 1) ? vb : va;
        float4 (*nxt)[4] = (t & 1) ? va : vb;
        if (t + 1 < BATCH2) {               // prefetch next 2 rows FIRST
            const float* nb = base + (size_t)((t + 1) * 2) * H_;
#pragma unroll
            for (int r = 0; r < 2; ++r)
#pragma unroll
                for (int q = 0; q < 4; ++q)
                    nxt[r][q] = *(const float4*)(nb + (size_t)r * H_ + q * 256);
        }
        float d0 = cur[0][0].x * w[0].x + cur[0][0].y * w[0].y
                 + cur[0][0].z * w[0].z + cur[0][0].w * w[0].w;
        float d1 = cur[1][0].x * w[0].x + cur[1][0].y * w[0].y
                 + cur[1][0].z * w[0].z + cur[1][0].w * w[0].w;
#pragma unroll
        for (int q = 1; q < 4; ++q) {
            d0 += cur[0][q].x * w[q].x + cur[0][q].y * w[q].y
                + cur[0][q].z * w[q].z + cur[0][q].w * w[q].w;
            d1 += cur[1][q].x * w[q].x + cur[1][q].y * w[q].y
                + cur[1][q].z * w[q].z + cur[1][q].w * w[q].w;
        }
#pragma unroll
        for (int off = 32; off >= 1; off >>= 1) {
            d0 += __shfl_xor(d0, off, 64);
            d1 += __shfl_xor(d1, off, 64);
        }
        const float e0 = __expf(d0), e1 = __expf(d1);
        if (lane == 0)
            *(float2*)(esc + (size_t)b * S_ + s0 + t * 2) = make_float2(e0, e1);
        l += e0 + e1;
#pragma unroll
        for (int q = 0; q < 4; ++q) {
            acc[q].x = fmaf(e0, cur[0][q].x, fmaf(e1, cur[1][q].x, acc[q].x));
            acc[q].y = fmaf(e0, cur[0][q].y, fmaf(e1, cur[1][q].y, acc[q].y));
            acc[q].z = fmaf(e0, cur[0][q].z, fmaf(e1, cur[1][q].z, acc[q].z));
            acc[q].w = fmaf(e0, cur[0][q].w, fmaf(e1, cur[1][q].w, acc[q].w));
        }
    }

    // block-level combine: 4 waves -> 1 partial row
    __shared__ float red[4 * H_];
    __shared__ float lred[4];
    float* my = red + wave * H_ + lane * 4;
#pragma unroll
    for (int q = 0; q < 4; ++q) *(float4*)(my + q * 256) = acc[q];
    if (lane == 0) lred[wave] = l;
    __syncthreads();

    const int h = tid * 4;                  // 256 threads x float4 = 1024
    float4 s0v = *(const float4*)(red + 0 * H_ + h);
    float4 s1v = *(const float4*)(red + 1 * H_ + h);
    float4 s2v = *(const float4*)(red + 2 * H_ + h);
    float4 s3v = *(const float4*)(red + 3 * H_ + h);
    float4 sm;
    sm.x = (s0v.x + s1v.x) + (s2v.x + s3v.x);
    sm.y = (s0v.y + s1v.y) + (s2v.y + s3v.y);
    sm.z = (s0v.z + s1v.z) + (s2v.z + s3v.z);
    sm.w = (s0v.w + s1v.w) + (s2v.w + s3v.w);
    *(float4*)(part + (size_t)blockIdx.x * H_ + h) = sm;
    if (tid == 0) lblk[blockIdx.x] = (lred[0] + lred[1]) + (lred[2] + lred[3]);
}

// context[b,h] = (sum_j part[b*32+j][h]) / L_b
__global__ __launch_bounds__(256) void combine_k(
    const float* __restrict__ part, const float* __restrict__ lblk,
    float* __restrict__ ctx_out)
{
    const int b = blockIdx.x;
    const int h = blockIdx.y * 256 + threadIdx.x;
    float L = 0.f;
#pragma unroll
    for (int j = 0; j < BLK_PER_B; ++j) L += lblk[b * BLK_PER_B + j];
    float sum = 0.f;
#pragma unroll
    for (int j = 0; j < BLK_PER_B; ++j)
        sum += part[(size_t)(b * BLK_PER_B + j) * H_ + h];
    ctx_out[(size_t)b * H_ + h] = sum / L;
}

__global__ __launch_bounds__(256) void attn_k(
    const float* __restrict__ esc, const float* __restrict__ lblk,
    float* __restrict__ attn_out)
{
    const int i = blockIdx.x * 256 + threadIdx.x;  // float4 index, 0..16383
    const int b = i >> 9;
    float L = 0.f;
#pragma unroll
    for (int j = 0; j < BLK_PER_B; ++j) L += lblk[b * BLK_PER_B + j];
    const float invL = 1.0f / L;
    const float4 e = ((const float4*)esc)[i];
    float4 o;
    o.x = e.x * invL; o.y = e.y * invL; o.z = e.z * invL; o.w = e.w * invL;
    ((float4*)attn_out)[i] = o;
}

extern "C" void kernel_launch(void* const* d_in, const int* in_sizes, int n_in,
                              void* d_out, int out_size, void* d_ws, size_t ws_size,
                              hipStream_t stream)
{
    const float* lstm = (const float*)d_in[0];
    // d_in[1]=final_hidden, d_in[3]=b: irrelevant under softmax shift-invariance
    const float* W    = (const float*)d_in[2];

    float* out  = (float*)d_out;
    float* ctx  = out;               // 32*1024
    float* attn = out + B_ * H_;     // 32*2048

    float* ws   = (float*)d_ws;
    float* esc  = ws;                              // 65536 floats (exp(score))
    float* part = ws + (size_t)B_ * S_;            // 1024*1024 floats
    float* lblk = part + (size_t)NBLK * H_;        // 1024 floats

    fused_pass<<<NBLK, 256, 0, stream>>>(lstm, W, esc, part, lblk);
    combine_k<<<dim3(B_, H_ / 256), 256, 0, stream>>>(part, lblk, ctx);
    attn_k<<<(B_ * S_) / (4 * 256), 256, 0, stream>>>(esc, lblk, attn);
}

// Round 4
// 363.045 us; speedup vs baseline: 1.1124x; 1.0073x over previous
//
#include <hip/hip_runtime.h>

// AdditiveAttention: B=32, S=2048, H=1024, fp32.
// attn = softmax_s(lstm . w1)   (fh.w2 + b per-row constant -> softmax-invariant, skipped)
// context = attn . lstm
// R4: DPP wave-reduction (VALU pipe, ~5x shorter dependent chain than ds_swizzle
// butterfly) as the decisive latency-vs-BW probe; combine+attn merged into one
// epilogue kernel.

#define B_ 32
#define S_ 2048
#define H_ 1024
#define ROWS 16
#define BATCH2 (ROWS / 2)                // 8 double-buffered 2-row batches
#define WAVES_PER_BATCH (S_ / ROWS)      // 128
#define NWAVE (B_ * WAVES_PER_BATCH)     // 4096
#define NBLK (NWAVE / 4)                 // 1024 blocks (4 per CU)
#define BLK_PER_B (NBLK / B_)            // 32 partial rows per batch row

// one DPP-add step: x += dpp_move(x, ctrl); bound_ctrl=1 -> OOB lanes contribute 0
#define DPP_ADD(x, ctrl)                                                        \
    (x) += __int_as_float(__builtin_amdgcn_update_dpp(                          \
        0, __float_as_int(x), (ctrl), 0xF, 0xF, true))

__device__ inline float wave_sum_bcast(float x) {
    DPP_ADD(x, 0x0B1);  // quad_perm [1,0,3,2]  : +lane^1
    DPP_ADD(x, 0x04E);  // quad_perm [2,3,0,1]  : +lane^2
    DPP_ADD(x, 0x141);  // row_half_mirror      : +lane^4
    DPP_ADD(x, 0x140);  // row_mirror           : +lane^8
    DPP_ADD(x, 0x142);  // row_bcast:15         : combine row pairs
    DPP_ADD(x, 0x143);  // row_bcast:31         : lane 63 = full 64-lane sum
    return __int_as_float(__builtin_amdgcn_readlane(__float_as_int(x), 63));
}

__global__ __launch_bounds__(256) void fused_pass(
    const float* __restrict__ lstm, const float* __restrict__ W,
    float* __restrict__ esc, float* __restrict__ part, float* __restrict__ lblk)
{
    const int tid  = threadIdx.x;
    const int wave = tid >> 6;
    const int lane = tid & 63;
    const int gw   = blockIdx.x * 4 + wave;   // 0..4095
    const int b    = gw >> 7;
    const int s0   = (gw & 127) * ROWS;

    float4 w[4];
#pragma unroll
    for (int q = 0; q < 4; ++q)
        w[q] = *(const float4*)(W + q * 256 + lane * 4);

    float4 acc[4];
#pragma unroll
    for (int q = 0; q < 4; ++q) acc[q] = make_float4(0.f, 0.f, 0.f, 0.f);
    float l = 0.f;

    const float* base = lstm + ((size_t)b * S_ + s0) * H_ + lane * 4;

    float4 va[2][4], vb[2][4];
#pragma unroll
    for (int r = 0; r < 2; ++r)
#pragma unroll
        for (int q = 0; q < 4; ++q)
            va[r][q] = *(const float4*)(base + (size_t)r * H_ + q * 256);

#pragma unroll
    for (int t = 0; t < BATCH2; ++t) {
        float4 (*cur)[4] = (t & 1) ? vb : va;
        float4 (*nxt)[4] = (t & 1) ? va : vb;
        if (t + 1 < BATCH2) {               // prefetch next 2 rows first
            const float* nb = base + (size_t)((t + 1) * 2) * H_;
#pragma unroll
            for (int r = 0; r < 2; ++r)
#pragma unroll
                for (int q = 0; q < 4; ++q)
                    nxt[r][q] = *(const float4*)(nb + (size_t)r * H_ + q * 256);
        }
        float d0 = cur[0][0].x * w[0].x + cur[0][0].y * w[0].y
                 + cur[0][0].z * w[0].z + cur[0][0].w * w[0].w;
        float d1 = cur[1][0].x * w[0].x + cur[1][0].y * w[0].y
                 + cur[1][0].z * w[0].z + cur[1][0].w * w[0].w;
#pragma unroll
        for (int q = 1; q < 4; ++q) {
            d0 += cur[0][q].x * w[q].x + cur[0][q].y * w[q].y
                + cur[0][q].z * w[q].z + cur[0][q].w * w[q].w;
            d1 += cur[1][q].x * w[q].x + cur[1][q].y * w[q].y
                + cur[1][q].z * w[q].z + cur[1][q].w * w[q].w;
        }
        const float s0d = wave_sum_bcast(d0);   // two interleaved DPP chains (ILP 2)
        const float s1d = wave_sum_bcast(d1);
        const float e0 = __expf(s0d), e1 = __expf(s1d);
        if (lane == 0)
            *(float2*)(esc + (size_t)b * S_ + s0 + t * 2) = make_float2(e0, e1);
        l += e0 + e1;
#pragma unroll
        for (int q = 0; q < 4; ++q) {
            acc[q].x = fmaf(e0, cur[0][q].x, fmaf(e1, cur[1][q].x, acc[q].x));
            acc[q].y = fmaf(e0, cur[0][q].y, fmaf(e1, cur[1][q].y, acc[q].y));
            acc[q].z = fmaf(e0, cur[0][q].z, fmaf(e1, cur[1][q].z, acc[q].z));
            acc[q].w = fmaf(e0, cur[0][q].w, fmaf(e1, cur[1][q].w, acc[q].w));
        }
    }

    // block-level combine: 4 waves -> 1 partial row
    __shared__ float red[4 * H_];
    __shared__ float lred[4];
    float* my = red + wave * H_ + lane * 4;
#pragma unroll
    for (int q = 0; q < 4; ++q) *(float4*)(my + q * 256) = acc[q];
    if (lane == 0) lred[wave] = l;
    __syncthreads();

    const int h = tid * 4;
    float4 s0v = *(const float4*)(red + 0 * H_ + h);
    float4 s1v = *(const float4*)(red + 1 * H_ + h);
    float4 s2v = *(const float4*)(red + 2 * H_ + h);
    float4 s3v = *(const float4*)(red + 3 * H_ + h);
    float4 sm;
    sm.x = (s0v.x + s1v.x) + (s2v.x + s3v.x);
    sm.y = (s0v.y + s1v.y) + (s2v.y + s3v.y);
    sm.z = (s0v.z + s1v.z) + (s2v.z + s3v.z);
    sm.w = (s0v.w + s1v.w) + (s2v.w + s3v.w);
    *(float4*)(part + (size_t)blockIdx.x * H_ + h) = sm;
    if (tid == 0) lblk[blockIdx.x] = (lred[0] + lred[1]) + (lred[2] + lred[3]);
}

// blocks 0..127: context ; blocks 128..191: attn
__global__ __launch_bounds__(256) void epilogue_k(
    const float* __restrict__ part, const float* __restrict__ lblk,
    const float* __restrict__ esc, float* __restrict__ ctx_out,
    float* __restrict__ attn_out)
{
    const int blk = blockIdx.x;
    if (blk < 128) {
        const int b = blk >> 2;
        const int h = (blk & 3) * 256 + threadIdx.x;
        float L = 0.f;
#pragma unroll
        for (int j = 0; j < BLK_PER_B; ++j) L += lblk[b * BLK_PER_B + j];
        float sum = 0.f;
#pragma unroll
        for (int j = 0; j < BLK_PER_B; ++j)
            sum += part[(size_t)(b * BLK_PER_B + j) * H_ + h];
        ctx_out[(size_t)b * H_ + h] = sum / L;
    } else {
        const int i = (blk - 128) * 256 + threadIdx.x;  // float4 idx, 0..16383
        const int b = i >> 9;
        float L = 0.f;
#pragma unroll
        for (int j = 0; j < BLK_PER_B; ++j) L += lblk[b * BLK_PER_B + j];
        const float invL = 1.0f / L;
        const float4 e = ((const float4*)esc)[i];
        float4 o;
        o.x = e.x * invL; o.y = e.y * invL; o.z = e.z * invL; o.w = e.w * invL;
        ((float4*)attn_out)[i] = o;
    }
}

extern "C" void kernel_launch(void* const* d_in, const int* in_sizes, int n_in,
                              void* d_out, int out_size, void* d_ws, size_t ws_size,
                              hipStream_t stream)
{
    const float* lstm = (const float*)d_in[0];
    // d_in[1]=final_hidden, d_in[3]=b: irrelevant under softmax shift-invariance
    const float* W    = (const float*)d_in[2];

    float* out  = (float*)d_out;
    float* ctx  = out;               // 32*1024
    float* attn = out + B_ * H_;     // 32*2048

    float* ws   = (float*)d_ws;
    float* esc  = ws;                              // 65536 floats (exp(score))
    float* part = ws + (size_t)B_ * S_;            // 1024*1024 floats
    float* lblk = part + (size_t)NBLK * H_;        // 1024 floats

    fused_pass<<<NBLK, 256, 0, stream>>>(lstm, W, esc, part, lblk);
    epilogue_k<<<192, 256, 0, stream>>>(part, lblk, esc, ctx, attn);
}